// Round 5
// baseline (231.377 us; speedup 1.0000x reference)
//
#include <hip/hip_runtime.h>

// Morton decode: out[b,c,i,j] = x[b,c,ij], i = odd bits of ij, j = even bits.
// B=8, C=64, L=65536 (S=256), fp32.
//
// R6: STEADY-STATE ablation. R1-R5 pinned ~2.5 TB/s across write-pattern /
// NT-policy / MLP / occupancy / read-density changes. The last property a
// 6.3 TB/s copy has that none of them had: persistent waves keeping reads
// AND writes concurrently in flight. One-shot blocks alternate load-burst /
// store-burst and drain the pipeline at every wave death.
//
// Here: 2048 blocks (8/CU, 32 waves/CU @ ~56 VGPR), each processes 4 Morton
// tiles = one contiguous 64 KB source range (Morton source is linear in
// tile id). Register double-buffer, software-pipelined: loads for tile k+1
// are issued BEFORE the stores of tile k, so the compiler's counted
// vmcnt(4) wait lets stores(k) overlap loads(k+1) -- continuous two-way
// traffic, copy-style. No LDS, no barriers. Shuffle/store mapping is R1's
// (harness-verified): per tile, thread t owns a 4x4 patch; per store
// instruction the wave covers 8 rows x 128 B full cachelines.

typedef float f32x4 __attribute__((ext_vector_type(4)));

__device__ __forceinline__ unsigned compact1by1(unsigned x) {
    // compact the even-position bits of x into the low bits
    x &= 0x55555555u;
    x = (x ^ (x >> 1)) & 0x33333333u;
    x = (x ^ (x >> 2)) & 0x0f0f0f0fu;
    x = (x ^ (x >> 4)) & 0x00ff00ffu;
    return x;
}

__global__ __launch_bounds__(256) void Morton_decode_69312182223578_kernel(
        const float* __restrict__ x, float* __restrict__ out) {
    const unsigned t  = threadIdx.x;
    // t bits (0..7) = j2,i2,j3,i3,j4,i4,j5,i5
    const unsigned Jh = compact1by1(t);        // j2..j5 (4 bits)
    const unsigned Ih = compact1by1(t >> 1);   // i2..i5 (4 bits)

    const unsigned T0 = blockIdx.x << 2;       // first of 4 tile ids
    const unsigned bc = T0 >> 4;               // image index (constant: T0..T0+3 share it)
    float* const oimg = out + (size_t)bc * 65536u;
    const f32x4* const xv = (const f32x4*)x;

    f32x4 v[2][4];                             // double-buffered tile data
    {   // prologue: loads for tile T0 (64 B contiguous per lane)
        const f32x4* s = xv + ((size_t)T0 << 10) + 4u * t;
        v[0][0] = s[0]; v[0][1] = s[1]; v[0][2] = s[2]; v[0][3] = s[3];
    }

#pragma unroll
    for (unsigned k = 0; k < 4; ++k) {         // fully unrolled: all v[][] static
        const unsigned cur = k & 1u;
        if (k < 3) {                           // prefetch tile k+1 BEFORE stores of k
            const f32x4* s = xv + ((size_t)(T0 + k + 1u) << 10) + 4u * t;
            v[cur ^ 1u][0] = s[0]; v[cur ^ 1u][1] = s[1];
            v[cur ^ 1u][2] = s[2]; v[cur ^ 1u][3] = s[3];
        }

        // destination tile coords: tm bit0=tj0, bit1=ti0, bit2=tj1, bit3=ti1
        const unsigned tm = (T0 + k) & 15u;
        const unsigned tj = (tm & 1u) | ((tm >> 1) & 2u);
        const unsigned ti = ((tm >> 1) & 1u) | ((tm >> 2) & 2u);
        float* p = oimg + (size_t)(ti * 64u + 4u * Ih) * 256u + (tj * 64u + 4u * Jh);

        // Quad m bits: (j1,i1). m=0:(r0,c0) m=1:(r0,c2) m=2:(r2,c0) m=3:(r2,c2)
        // Within a quad: .x=(r,c) .y=(r,c+1) .z=(r+1,c) .w=(r+1,c+1)
        const f32x4 a0 = v[cur][0], a1 = v[cur][1], a2 = v[cur][2], a3 = v[cur][3];
        f32x4 r;
        r = (f32x4){a0.x, a0.y, a1.x, a1.y}; *(f32x4*)(p)       = r;
        r = (f32x4){a0.z, a0.w, a1.z, a1.w}; *(f32x4*)(p + 256) = r;
        r = (f32x4){a2.x, a2.y, a3.x, a3.y}; *(f32x4*)(p + 512) = r;
        r = (f32x4){a2.z, a2.w, a3.z, a3.w}; *(f32x4*)(p + 768) = r;
    }
}

extern "C" void kernel_launch(void* const* d_in, const int* in_sizes, int n_in,
                              void* d_out, int out_size, void* d_ws, size_t ws_size,
                              hipStream_t stream) {
    const float* x = (const float*)d_in[0];
    float* out = (float*)d_out;
    // 512 images * 16 tiles = 8192 tiles; 4 tiles per block -> 2048 blocks
    // (8 blocks/CU, persistent-style pipelined loop, no tail)
    Morton_decode_69312182223578_kernel<<<2048, 256, 0, stream>>>(x, out);
}